// Round 1
// baseline (283.486 us; speedup 1.0000x reference)
//
#include <hip/hip_runtime.h>
#include <math.h>

#define D 128

// M[j][k] = sum_i Wq[i][j] * Wk[i][k]   (so scores = m^T M x)
// WoT[j][k] = Wo[k][j]                  (so out[i] = sum_j y[j] * WoT[j][i])
__global__ void k_prep(const float* __restrict__ Wq, const float* __restrict__ Wk,
                       const float* __restrict__ Wo, float* __restrict__ M,
                       float* __restrict__ WoT) {
  int j = blockIdx.x, k = threadIdx.x;
  float acc = 0.f;
#pragma unroll 8
  for (int i = 0; i < D; ++i) acc = fmaf(Wq[i * D + j], Wk[i * D + k], acc);
  M[j * D + k] = acc;
  WoT[j * D + k] = Wo[k * D + j];
}

// starts[s] = first element index of segment s; starts[S] = V. idx is sorted.
__global__ void k_starts(const int* __restrict__ idx, int* __restrict__ starts,
                         int V, int S) {
  int v = blockIdx.x * blockDim.x + threadIdx.x;
  if (v >= V) return;
  int c = idx[v];
  int p = (v == 0) ? -1 : idx[v - 1];
  for (int s = p + 1; s <= c; ++s) starts[s] = v;
  if (v == V - 1) {
    for (int s = c + 1; s <= S; ++s) starts[s] = V;
  }
}

// mean[s][:] = mean of x rows in run [starts[s], starts[s+1]). 32 threads/segment.
__global__ void k_means(const float* __restrict__ x, const int* __restrict__ starts,
                        float* __restrict__ mean, int S) {
  int tid = blockIdx.x * blockDim.x + threadIdx.x;
  if (tid >= S * 32) return;
  int s = tid >> 5, g = tid & 31;
  int b = starts[s], e = starts[s + 1];
  float4 a = make_float4(0.f, 0.f, 0.f, 0.f);
  for (int v = b; v < e; ++v) {
    float4 xv = *(const float4*)(x + (size_t)v * D + g * 4);
    a.x += xv.x; a.y += xv.y; a.z += xv.z; a.w += xv.w;
  }
  float inv = (e > b) ? 1.f / (float)(e - b) : 0.f;
  a.x *= inv; a.y *= inv; a.z *= inv; a.w *= inv;
  *(float4*)(mean + (size_t)s * D + g * 4) = a;
}

// out[s][c] = sum_j in[s][j] * B[j][c], B (128x128) staged in LDS.
__global__ void k_rowmat(const float* __restrict__ in, const float* __restrict__ B,
                         float* __restrict__ out, int S) {
  __shared__ float Bl[D * D];
  for (int i = threadIdx.x; i < D * D / 4; i += blockDim.x)
    ((float4*)Bl)[i] = ((const float4*)B)[i];
  __syncthreads();
  int nth = gridDim.x * blockDim.x;
  for (int t = blockIdx.x * blockDim.x + threadIdx.x; t < S * 32; t += nth) {
    int s = t >> 5, g = t & 31;
    const float4* rowv = (const float4*)(in + (size_t)s * D);
    float4 a = make_float4(0.f, 0.f, 0.f, 0.f);
#pragma unroll 8
    for (int j4 = 0; j4 < D / 4; ++j4) {
      float4 mv = rowv[j4];
      float4 b0 = *(const float4*)(Bl + (j4 * 4 + 0) * D + g * 4);
      float4 b1 = *(const float4*)(Bl + (j4 * 4 + 1) * D + g * 4);
      float4 b2 = *(const float4*)(Bl + (j4 * 4 + 2) * D + g * 4);
      float4 b3 = *(const float4*)(Bl + (j4 * 4 + 3) * D + g * 4);
      a.x = fmaf(mv.x, b0.x, a.x); a.y = fmaf(mv.x, b0.y, a.y);
      a.z = fmaf(mv.x, b0.z, a.z); a.w = fmaf(mv.x, b0.w, a.w);
      a.x = fmaf(mv.y, b1.x, a.x); a.y = fmaf(mv.y, b1.y, a.y);
      a.z = fmaf(mv.y, b1.z, a.z); a.w = fmaf(mv.y, b1.w, a.w);
      a.x = fmaf(mv.z, b2.x, a.x); a.y = fmaf(mv.z, b2.y, a.y);
      a.z = fmaf(mv.z, b2.z, a.z); a.w = fmaf(mv.z, b2.w, a.w);
      a.x = fmaf(mv.w, b3.x, a.x); a.y = fmaf(mv.w, b3.y, a.y);
      a.z = fmaf(mv.w, b3.z, a.z); a.w = fmaf(mv.w, b3.w, a.w);
    }
    *(float4*)(out + (size_t)s * D + g * 4) = a;
  }
}

// scores[v] = t[idx[v]] . x[v]; 32 lanes per element, shuffle reduce.
__global__ void k_scores(const float* __restrict__ x, const float* __restrict__ t,
                         const int* __restrict__ idx, float* __restrict__ scores,
                         int V) {
  long long gtid = (long long)blockIdx.x * blockDim.x + threadIdx.x;
  int v = (int)(gtid >> 5), g = (int)(gtid & 31);
  if (v >= V) return;
  int s = idx[v];
  float4 xv = *(const float4*)(x + (size_t)v * D + g * 4);
  float4 tv = *(const float4*)(t + (size_t)s * D + g * 4);
  float p = xv.x * tv.x + xv.y * tv.y + xv.z * tv.z + xv.w * tv.w;
  p += __shfl_xor(p, 16);
  p += __shfl_xor(p, 8);
  p += __shfl_xor(p, 4);
  p += __shfl_xor(p, 2);
  p += __shfl_xor(p, 1);
  if (g == 0) scores[v] = p;
}

// Per-segment softmax stats: max and 1/sum(exp(.-max)). Thread per segment.
__global__ void k_stats(const float* __restrict__ scores, const int* __restrict__ starts,
                        float* __restrict__ smax, float* __restrict__ sinvden, int S) {
  int s = blockIdx.x * blockDim.x + threadIdx.x;
  if (s >= S) return;
  int b = starts[s], e = starts[s + 1];
  float mx = -INFINITY;
  for (int v = b; v < e; ++v) mx = fmaxf(mx, scores[v]);
  float den = 0.f;
  for (int v = b; v < e; ++v) den += __expf(scores[v] - mx);
  smax[s] = mx;
  sinvden[s] = (e > b) ? 1.f / den : 0.f;
}

// y[s][:] = sum_v prob_v * x[v][:]. 32 threads/segment.
__global__ void k_y(const float* __restrict__ x, const float* __restrict__ scores,
                    const float* __restrict__ smax, const float* __restrict__ sinvden,
                    const int* __restrict__ starts, float* __restrict__ y, int S) {
  int tid = blockIdx.x * blockDim.x + threadIdx.x;
  if (tid >= S * 32) return;
  int s = tid >> 5, g = tid & 31;
  int b = starts[s], e = starts[s + 1];
  float mx = smax[s];
  float inv = sinvden[s];
  float4 a = make_float4(0.f, 0.f, 0.f, 0.f);
  for (int v = b; v < e; ++v) {
    float p = __expf(scores[v] - mx) * inv;
    float4 xv = *(const float4*)(x + (size_t)v * D + g * 4);
    a.x = fmaf(p, xv.x, a.x); a.y = fmaf(p, xv.y, a.y);
    a.z = fmaf(p, xv.z, a.z); a.w = fmaf(p, xv.w, a.w);
  }
  *(float4*)(y + (size_t)s * D + g * 4) = a;
}

extern "C" void kernel_launch(void* const* d_in, const int* in_sizes, int n_in,
                              void* d_out, int out_size, void* d_ws, size_t ws_size,
                              hipStream_t stream) {
  const float* x = (const float*)d_in[0];
  const int* idx = (const int*)d_in[1];
  const float* Wq = (const float*)d_in[3];
  const float* Wk = (const float*)d_in[4];
  const float* Wo = (const float*)d_in[5];
  float* out = (float*)d_out;
  const int V = in_sizes[1];
  const int S = out_size / D;

  char* ws = (char*)d_ws;
  float* M = (float*)(ws + 0);            // 64 KB
  float* WoT = (float*)(ws + 65536);      // 64 KB
  int* starts = (int*)(ws + 131072);      // (S+1)*4 B
  size_t base = (131072 + 4 * (size_t)(S + 1) + 255) & ~(size_t)255;
  // Region A: t (read by k_scores), later reused as y.
  float* t_buf = (float*)(ws + base);
  float* y = t_buf;
  // Region B: mean (dead after first k_rowmat), reused as scores/smax/sinvden.
  float* mean = (float*)(ws + base + (size_t)S * D * 4);
  float* scores = mean;
  float* smax = (float*)((char*)mean + (size_t)V * 4);
  float* sinvden = smax + S;

  hipLaunchKernelGGL(k_prep, dim3(D), dim3(D), 0, stream, Wq, Wk, Wo, M, WoT);
  hipLaunchKernelGGL(k_starts, dim3((V + 255) / 256), dim3(256), 0, stream, idx, starts, V, S);
  hipLaunchKernelGGL(k_means, dim3((S * 32 + 255) / 256), dim3(256), 0, stream, x, starts, mean, S);
  hipLaunchKernelGGL(k_rowmat, dim3(512), dim3(256), 0, stream, mean, M, t_buf, S);
  {
    long long tot = (long long)V * 32;
    int blocks = (int)((tot + 255) / 256);
    hipLaunchKernelGGL(k_scores, dim3(blocks), dim3(256), 0, stream, x, t_buf, idx, scores, V);
  }
  hipLaunchKernelGGL(k_stats, dim3((S + 255) / 256), dim3(256), 0, stream, scores, starts, smax, sinvden, S);
  hipLaunchKernelGGL(k_y, dim3((S * 32 + 255) / 256), dim3(256), 0, stream, x, scores, smax, sinvden, starts, y, S);
  hipLaunchKernelGGL(k_rowmat, dim3(512), dim3(256), 0, stream, y, WoT, out, S);
}